// Round 3
// baseline (116.604 us; speedup 1.0000x reference)
//
#include <hip/hip_runtime.h>

#define HW   16384            // 128*128
#define NPIX 65536            // 4*HW

typedef _Float16 f16x2 __attribute__((ext_vector_type(2)));

#if __has_builtin(__builtin_amdgcn_fdot2)
#define DOT2(a, b, c) __builtin_amdgcn_fdot2((a), (b), (c), false)
#else
__device__ __forceinline__ float dot2_fb(f16x2 a, f16x2 b, float c) {
    return fmaf((float)a.x, (float)b.x, fmaf((float)a.y, (float)b.y, c));
}
#define DOT2(a, b, c) dot2_fb((a), (b), (c))
#endif

#if __has_builtin(__builtin_amdgcn_exp2f)
#define EXP2F(x) __builtin_amdgcn_exp2f(x)
#else
#define EXP2F(x) exp2f(x)
#endif

__device__ __forceinline__ unsigned packh2(float a, float b) {
    f16x2 h; h.x = (_Float16)a; h.y = (_Float16)b;
    return __builtin_bit_cast(unsigned, h);
}
__device__ __forceinline__ f16x2 bch(unsigned u) {
    return __builtin_bit_cast(f16x2, u);
}

// ---------------------------------------------------------------------------
// Pass 1: 1x1 convs (f1,f2: 16ch each), |f2|^2, bilinear-upsampled out.
// delta (64 f32) held in VGPRs per thread; weight rows are consecutive uniform
// addresses -> s_load_dwordx16 from scalar cache. Outputs packed fp16:
//   f1p4/f2p4: uint4[2][NPIX] (SoA planes, 16B each = 8 halves)
//   recp: float2[NPIX] = {bits(half2{o0,o1}), f2sq(f32)}
// ---------------------------------------------------------------------------
__global__ __launch_bounds__(256) void pass1_kernel(
    const float* __restrict__ delta, const float* __restrict__ outlo,
    const float* __restrict__ w1, const float* __restrict__ b1,
    const float* __restrict__ w2, const float* __restrict__ b2,
    uint4* __restrict__ f1p4, uint4* __restrict__ f2p4, float2* __restrict__ recp)
{
    const int g = blockIdx.x * 256 + threadIdx.x;   // 0..65535
    const int n = g >> 14;
    const int p = g & (HW - 1);

    float acc1[16], acc2[16];
#pragma unroll
    for (int o = 0; o < 16; ++o) { acc1[o] = b1[o]; acc2[o] = b2[o]; }

    const float* db = delta + (size_t)n * 64 * HW + p;
#pragma unroll
    for (int cc = 0; cc < 4; ++cc) {
        float d[16];
#pragma unroll
        for (int j = 0; j < 16; ++j) d[j] = db[(cc * 16 + j) * HW];
#pragma unroll
        for (int o = 0; o < 16; ++o) {
            const float* w1r = w1 + o * 64 + cc * 16;   // 16 consecutive floats
            const float* w2r = w2 + o * 64 + cc * 16;
#pragma unroll
            for (int j = 0; j < 16; ++j) {
                acc1[o] = fmaf(w1r[j], d[j], acc1[o]);
                acc2[o] = fmaf(w2r[j], d[j], acc2[o]);
            }
        }
    }

    float f2sq = 0.f;
#pragma unroll
    for (int o = 0; o < 16; ++o) f2sq = fmaf(acc2[o], acc2[o], f2sq);

    uint4 q;
    q.x = packh2(acc1[0], acc1[1]);  q.y = packh2(acc1[2], acc1[3]);
    q.z = packh2(acc1[4], acc1[5]);  q.w = packh2(acc1[6], acc1[7]);
    f1p4[g] = q;
    q.x = packh2(acc1[8], acc1[9]);  q.y = packh2(acc1[10], acc1[11]);
    q.z = packh2(acc1[12], acc1[13]);q.w = packh2(acc1[14], acc1[15]);
    f1p4[NPIX + g] = q;
    q.x = packh2(acc2[0], acc2[1]);  q.y = packh2(acc2[2], acc2[3]);
    q.z = packh2(acc2[4], acc2[5]);  q.w = packh2(acc2[6], acc2[7]);
    f2p4[g] = q;
    q.x = packh2(acc2[8], acc2[9]);  q.y = packh2(acc2[10], acc2[11]);
    q.z = packh2(acc2[12], acc2[13]);q.w = packh2(acc2[14], acc2[15]);
    f2p4[NPIX + g] = q;

    // bilinear align_corners upsample of out [N,2,64,64] at (y,x)
    const int y = p >> 7, x = p & 127;
    const float ys = (float)(y * 63) / 127.0f;
    const float xs = (float)(x * 63) / 127.0f;
    const int iy0 = (int)ys, ix0 = (int)xs;
    const float fy = ys - (float)iy0, fx = xs - (float)ix0;
    const int iy1 = min(iy0 + 1, 63), ix1 = min(ix0 + 1, 63);
    const float* ob = outlo + n * 2 * 4096;
    float o01[2];
#pragma unroll
    for (int cc = 0; cc < 2; ++cc) {
        const float* oc = ob + cc * 4096;
        const float v00 = oc[iy0*64+ix0], v01 = oc[iy0*64+ix1];
        const float v10 = oc[iy1*64+ix0], v11 = oc[iy1*64+ix1];
        const float top = v00 + fx * (v01 - v00);
        const float bot = v10 + fx * (v11 - v10);
        o01[cc] = top + fy * (bot - top);
    }
    float2 rc;
    rc.x = __builtin_bit_cast(float, packh2(o01[0], o01[1]));
    rc.y = f2sq;
    recp[g] = rc;
}

// ---------------------------------------------------------------------------
// Pass 2: 16x16 tile, 128 threads, 2 adjacent px per thread. Halo 24x24
// staged in LDS as 48B records {8*half2 f2, half2 o01, f32 f2sq, pad}, row
// stride 25 records (uniform bank distribution for b128 reads). Shared tap
// columns serve both pixels; dots via v_dot2_f32_f16 (f32 accumulate);
// softmax un-normalized (delta_logits <= 0, exp cannot overflow); ab rows
// software-pipelined one dy ahead as float2.
// ---------------------------------------------------------------------------
__global__ __launch_bounds__(128) void pass2_kernel(
    const uint4* __restrict__ f1p4, const uint4* __restrict__ f2p4,
    const float2* __restrict__ recp, const float* __restrict__ ab,
    const float* __restrict__ gdp, const float* __restrict__ gsp,
    float* __restrict__ outp)
{
    __shared__ unsigned sh[24 * 25 * 12];   // 28.8 KB

    const int t = threadIdx.x;
    const int n = blockIdx.z;
    const int bx = blockIdx.x * 16, by = blockIdx.y * 16;

    // ---- fill 24x24 halo ----
#pragma unroll
    for (int s = 0; s < 5; ++s) {
        const int idx = t + s * 128;
        if (idx < 576) {
            const int hy = idx / 24, hx = idx - hy * 24;
            int gy = by - 4 + hy; gy = gy < 0 ? -gy : (gy > 127 ? 254 - gy : gy);
            int gx = bx - 4 + hx; gx = gx < 0 ? -gx : (gx > 127 ? 254 - gx : gx);
            const int g = n * HW + gy * 128 + gx;
            const uint4  q0 = f2p4[g];
            const uint4  q1 = f2p4[NPIX + g];
            const float2 rc = recp[g];
            const int b = (hy * 25 + hx) * 12;
            *(uint4*)&sh[b]     = q0;
            *(uint4*)&sh[b + 4] = q1;
            *(float2*)&sh[b + 8] = rc;
        }
    }
    __syncthreads();

    const float gd = gdp[0], gs = gsp[0];
    const float L2E = 1.44269504088896f;
    const int tx2 = t & 7, ty = t >> 3;
    const int x0 = bx + tx2 * 2, y = by + ty;
    const int p0 = y * 128 + x0;
    const int g0 = n * HW + p0;

    f16x2 f1a[8], f1b[8];
    {
        const uint4 A0 = f1p4[g0],     A1 = f1p4[NPIX + g0];
        const uint4 B0 = f1p4[g0 + 1], B1 = f1p4[NPIX + g0 + 1];
        f1a[0]=bch(A0.x); f1a[1]=bch(A0.y); f1a[2]=bch(A0.z); f1a[3]=bch(A0.w);
        f1a[4]=bch(A1.x); f1a[5]=bch(A1.y); f1a[6]=bch(A1.z); f1a[7]=bch(A1.w);
        f1b[0]=bch(B0.x); f1b[1]=bch(B0.y); f1b[2]=bch(B0.z); f1b[3]=bch(B0.w);
        f1b[4]=bch(B1.x); f1b[5]=bch(B1.y); f1b[6]=bch(B1.z); f1b[7]=bch(B1.w);
    }
    float f1sqa = 0.f, f1sqb = 0.f;
#pragma unroll
    for (int k = 0; k < 8; ++k) {
        f1sqa = DOT2(f1a[k], f1a[k], f1sqa);
        f1sqb = DOT2(f1b[k], f1b[k], f1sqb);
    }
    const float g2  = 2.0f * gd * L2E;
    const float mg  = -gd * L2E;
    const float gsl = gs * L2E;
    const float c0a = mg * f1sqa;
    const float c0b = mg * f1sqb;

    const float2* abp = (const float2*)ab + (size_t)n * 81 * (HW / 2) + (p0 >> 1);

    float2 cur[9], nxt[9];
#pragma unroll
    for (int j = 0; j < 9; ++j) cur[j] = abp[(size_t)j * (HW / 2)];

    float s0 = 0.f, x00 = 0.f, x01 = 0.f;
    float s1 = 0.f, x10 = 0.f, x11 = 0.f;

    for (int dy = 0; dy < 9; ++dy) {
        const int nr = (dy < 8) ? dy + 1 : 8;
#pragma unroll
        for (int j = 0; j < 9; ++j) nxt[j] = abp[(size_t)(nr * 9 + j) * (HW / 2)];

        const int rowb = ((ty + dy) * 25 + tx2 * 2) * 12;
#pragma unroll
        for (int dxc = 0; dxc < 10; ++dxc) {
            const int b = rowb + dxc * 12;
            const uint4  q0 = *(const uint4*)&sh[b];
            const uint4  q1 = *(const uint4*)&sh[b + 4];
            const float2 rc = *(const float2*)&sh[b + 8];
            f16x2 f2v[8];
            f2v[0]=bch(q0.x); f2v[1]=bch(q0.y); f2v[2]=bch(q0.z); f2v[3]=bch(q0.w);
            f2v[4]=bch(q1.x); f2v[5]=bch(q1.y); f2v[6]=bch(q1.z); f2v[7]=bch(q1.w);
            const f16x2 oh = bch(__builtin_bit_cast(unsigned, rc.x));
            const float o0f = (float)oh.x, o1f = (float)oh.y;
            const float f2s = rc.y;
            if (dxc <= 8) {            // pixel 0, tap column j = dxc
                float dt = 0.f;
#pragma unroll
                for (int k = 0; k < 8; ++k) dt = DOT2(f1a[k], f2v[k], dt);
                float e = fmaf(g2, dt, c0a);
                e = fmaf(mg, f2s, e);
                e = fmaf(gsl, cur[dxc].x, e);
                const float w = EXP2F(e);
                s0 += w; x00 = fmaf(w, o0f, x00); x01 = fmaf(w, o1f, x01);
            }
            if (dxc >= 1) {            // pixel 1, tap column j = dxc-1
                float dt = 0.f;
#pragma unroll
                for (int k = 0; k < 8; ++k) dt = DOT2(f1b[k], f2v[k], dt);
                float e = fmaf(g2, dt, c0b);
                e = fmaf(mg, f2s, e);
                e = fmaf(gsl, cur[dxc - 1].y, e);
                const float w = EXP2F(e);
                s1 += w; x10 = fmaf(w, o0f, x10); x11 = fmaf(w, o1f, x11);
            }
        }
#pragma unroll
        for (int j = 0; j < 9; ++j) cur[j] = nxt[j];
    }

    const float i0 = 1.0f / s0, i1 = 1.0f / s1;
    float2* o0p = (float2*)(outp + (size_t)(n * 2 + 0) * HW + p0);
    float2* o1p = (float2*)(outp + (size_t)(n * 2 + 1) * HW + p0);
    *o0p = make_float2(x00 * i0, x10 * i1);
    *o1p = make_float2(x01 * i0, x11 * i1);
}

extern "C" void kernel_launch(void* const* d_in, const int* in_sizes, int n_in,
                              void* d_out, int out_size, void* d_ws, size_t ws_size,
                              hipStream_t stream) {
    const float* delta = (const float*)d_in[0];   // [4,64,128,128]
    const float* outlo = (const float*)d_in[1];   // [4,2,64,64]
    const float* ab    = (const float*)d_in[2];   // [4,81,16384]
    const float* w1    = (const float*)d_in[3];   // [16,64]
    const float* b1    = (const float*)d_in[4];   // [16]
    const float* w2    = (const float*)d_in[5];   // [16,64]
    const float* b2    = (const float*)d_in[6];   // [16]
    const float* gd    = (const float*)d_in[7];   // scalar
    const float* gs    = (const float*)d_in[8];   // scalar
    float* outp = (float*)d_out;                  // [4,2,128,128]

    uint4*  f1p4 = (uint4*)d_ws;                  // 2 MiB (2 planes x NPIX)
    uint4*  f2p4 = f1p4 + (size_t)2 * NPIX;       // 2 MiB
    float2* recp = (float2*)(f2p4 + (size_t)2 * NPIX); // 512 KiB

    pass1_kernel<<<dim3(256), dim3(256), 0, stream>>>(delta, outlo, w1, b1, w2, b2,
                                                      f1p4, f2p4, recp);
    pass2_kernel<<<dim3(8, 8, 4), dim3(128), 0, stream>>>(f1p4, f2p4, recp, ab,
                                                          gd, gs, outp);
}

// Round 4
// 111.951 us; speedup vs baseline: 1.0416x; 1.0416x over previous
//
#include <hip/hip_runtime.h>

#define HW   16384            // 128*128
#define NPIX 65536            // 4*HW

typedef _Float16 f16x2 __attribute__((ext_vector_type(2)));

#if __has_builtin(__builtin_amdgcn_fdot2)
#define DOT2(a, b, c) __builtin_amdgcn_fdot2((a), (b), (c), false)
#else
__device__ __forceinline__ float dot2_fb(f16x2 a, f16x2 b, float c) {
    return fmaf((float)a.x, (float)b.x, fmaf((float)a.y, (float)b.y, c));
}
#define DOT2(a, b, c) dot2_fb((a), (b), (c))
#endif

#if __has_builtin(__builtin_amdgcn_exp2f)
#define EXP2F(x) __builtin_amdgcn_exp2f(x)
#else
#define EXP2F(x) exp2f(x)
#endif

__device__ __forceinline__ unsigned packh2(float a, float b) {
    f16x2 h; h.x = (_Float16)a; h.y = (_Float16)b;
    return __builtin_bit_cast(unsigned, h);
}
__device__ __forceinline__ f16x2 bch(unsigned u) {
    return __builtin_bit_cast(f16x2, u);
}

// ---------------------------------------------------------------------------
// Pass 1: 1x1 conv. blockIdx.y = which matrix (0: f1, 1: f2 + rec/bilinear).
// 512 blocks x 256 thr = 2048 waves = 2 waves/SIMD. delta (64 f32) prefetched
// into VGPRs; weight rows are 16-consecutive-f32 uniform reads -> s_load_dwordx16.
// ---------------------------------------------------------------------------
__global__ __launch_bounds__(256) void pass1_kernel(
    const float* __restrict__ delta, const float* __restrict__ outlo,
    const float* __restrict__ w1, const float* __restrict__ b1,
    const float* __restrict__ w2, const float* __restrict__ b2,
    uint4* __restrict__ f1p4, uint4* __restrict__ f2p4, float2* __restrict__ recp)
{
    const int m = blockIdx.y;
    const int g = blockIdx.x * 256 + threadIdx.x;   // 0..65535
    const int n = g >> 14;
    const int p = g & (HW - 1);

    const float* __restrict__ wm = m ? w2 : w1;
    const float* __restrict__ bm = m ? b2 : b1;

    float d[64];
    const float* db = delta + (size_t)n * 64 * HW + p;
#pragma unroll
    for (int c = 0; c < 64; ++c) d[c] = db[(size_t)c * HW];

    float acc[16];
#pragma unroll
    for (int o = 0; o < 16; ++o) {
        float a = bm[o];
        const float* wr = wm + o * 64;    // uniform, 64 consecutive f32
#pragma unroll
        for (int c = 0; c < 64; ++c) a = fmaf(wr[c], d[c], a);
        acc[o] = a;
    }

    uint4* dst = m ? f2p4 : f1p4;
    uint4 q;
    q.x = packh2(acc[0], acc[1]);   q.y = packh2(acc[2], acc[3]);
    q.z = packh2(acc[4], acc[5]);   q.w = packh2(acc[6], acc[7]);
    dst[g] = q;
    q.x = packh2(acc[8], acc[9]);   q.y = packh2(acc[10], acc[11]);
    q.z = packh2(acc[12], acc[13]); q.w = packh2(acc[14], acc[15]);
    dst[NPIX + g] = q;

    if (m) {
        float f2sq = 0.f;
#pragma unroll
        for (int o = 0; o < 16; ++o) f2sq = fmaf(acc[o], acc[o], f2sq);

        // bilinear align_corners upsample of out [N,2,64,64] at (y,x)
        const int y = p >> 7, x = p & 127;
        const float ys = (float)(y * 63) / 127.0f;
        const float xs = (float)(x * 63) / 127.0f;
        const int iy0 = (int)ys, ix0 = (int)xs;
        const float fy = ys - (float)iy0, fx = xs - (float)ix0;
        const int iy1 = min(iy0 + 1, 63), ix1 = min(ix0 + 1, 63);
        const float* ob = outlo + n * 2 * 4096;
        float o01[2];
#pragma unroll
        for (int cc = 0; cc < 2; ++cc) {
            const float* oc = ob + cc * 4096;
            const float v00 = oc[iy0*64+ix0], v01 = oc[iy0*64+ix1];
            const float v10 = oc[iy1*64+ix0], v11 = oc[iy1*64+ix1];
            const float top = v00 + fx * (v01 - v00);
            const float bot = v10 + fx * (v11 - v10);
            o01[cc] = top + fy * (bot - top);
        }
        float2 rc;
        rc.x = __builtin_bit_cast(float, packh2(o01[0], o01[1]));
        rc.y = f2sq;
        recp[g] = rc;
    }
}

// ---------------------------------------------------------------------------
// Pass 2: tile 16x8 px, VERTICAL pixel pairs (y, y+1) -> 64 pairs; 4 h-waves
// split the 10 halo rows (dyc = h, h+4, h+8). 512 blocks x 256 thr = 2 w/SIMD.
// Halo 24x16 staged plane-major (shA/shB: f2 fp16, shC: {o01h2, f2sq}):
// consecutive lanes -> consecutive 16B records -> conflict-free b128.
// Partial (s, x0, x1) per pixel reduced across the 4 h-waves via LDS.
// ---------------------------------------------------------------------------
__global__ __launch_bounds__(256) void pass2_kernel(
    const uint4* __restrict__ f1p4, const uint4* __restrict__ f2p4,
    const float2* __restrict__ recp, const float* __restrict__ ab,
    const float* __restrict__ gdp, const float* __restrict__ gsp,
    float* __restrict__ outp)
{
    __shared__ uint4  shA[384];     // f2 ch0-7   (idx = hy*24+hx)
    __shared__ uint4  shB[384];     // f2 ch8-15
    __shared__ float2 shC[384];     // {half2{o0,o1}, f2sq}
    __shared__ float  shP[6 * 4 * 64];  // [val][h][pair]

    const int t = threadIdx.x;
    const int n = blockIdx.z;
    const int bx = blockIdx.x * 16, by = blockIdx.y * 8;

    // ---- fill 24x16 halo ----
#pragma unroll
    for (int s = 0; s < 2; ++s) {
        const int idx = t + s * 256;
        if (idx < 384) {
            const int hy = idx / 24, hx = idx - hy * 24;
            int gy = by - 4 + hy; gy = gy < 0 ? -gy : (gy > 127 ? 254 - gy : gy);
            int gx = bx - 4 + hx; gx = gx < 0 ? -gx : (gx > 127 ? 254 - gx : gx);
            const int gg = n * HW + gy * 128 + gx;
            shA[idx] = f2p4[gg];
            shB[idx] = f2p4[NPIX + gg];
            shC[idx] = recp[gg];
        }
    }
    __syncthreads();

    const float gd = gdp[0], gs = gsp[0];
    const float L2E = 1.44269504088896f;
    const float g2 = 2.0f * gd * L2E, mg = -gd * L2E, gsl = gs * L2E;

    const int wh = t >> 6;          // 0..3 (one h per wave)
    const int l  = t & 63;          // pair index
    const int px = l & 15, pyr = l >> 4;
    const int p0 = (by + pyr * 2) * 128 + bx + px;   // upper pixel of pair
    const int g0 = n * HW + p0;

    f16x2 f1a[8], f1b[8];
    {
        const uint4 A0 = f1p4[g0],       A1 = f1p4[NPIX + g0];
        const uint4 B0 = f1p4[g0 + 128], B1 = f1p4[NPIX + g0 + 128];
        f1a[0]=bch(A0.x); f1a[1]=bch(A0.y); f1a[2]=bch(A0.z); f1a[3]=bch(A0.w);
        f1a[4]=bch(A1.x); f1a[5]=bch(A1.y); f1a[6]=bch(A1.z); f1a[7]=bch(A1.w);
        f1b[0]=bch(B0.x); f1b[1]=bch(B0.y); f1b[2]=bch(B0.z); f1b[3]=bch(B0.w);
        f1b[4]=bch(B1.x); f1b[5]=bch(B1.y); f1b[6]=bch(B1.z); f1b[7]=bch(B1.w);
    }
    float f1sqa = 0.f, f1sqb = 0.f;
#pragma unroll
    for (int k = 0; k < 8; ++k) {
        f1sqa = DOT2(f1a[k], f1a[k], f1sqa);
        f1sqb = DOT2(f1b[k], f1b[k], f1sqb);
    }
    const float c0a = mg * f1sqa;
    const float c0b = mg * f1sqb;

    float s0 = 0.f, x00 = 0.f, x01 = 0.f;
    float s1 = 0.f, x10 = 0.f, x11 = 0.f;

    const float* abn = ab + (size_t)n * 81 * HW;
    const int nrows = (wh < 2) ? 3 : 2;   // dyc = wh, wh+4, wh+8 (<=9)

    for (int r = 0; r < nrows; ++r) {
        const int dyc = wh + r * 4;            // 0..9, wave-uniform
        const bool has0 = (dyc <= 8);          // upper pixel taps row i=dyc
        const bool has1 = (dyc >= 1);          // lower pixel taps row i=dyc-1
        float a0v[9], a1v[9];
        if (has0) {
            const float* a0p = abn + (size_t)(dyc * 9) * HW + p0;
#pragma unroll
            for (int j = 0; j < 9; ++j) a0v[j] = a0p[(size_t)j * HW];
        }
        if (has1) {
            const float* a1p = abn + (size_t)((dyc - 1) * 9) * HW + p0 + 128;
#pragma unroll
            for (int j = 0; j < 9; ++j) a1v[j] = a1p[(size_t)j * HW];
        }
        const int rib = (pyr * 2 + dyc) * 24 + px;
#pragma unroll
        for (int j = 0; j < 9; ++j) {
            const uint4  q0 = shA[rib + j];
            const uint4  q1 = shB[rib + j];
            const float2 rc = shC[rib + j];
            f16x2 v0 = bch(q0.x), v1 = bch(q0.y), v2 = bch(q0.z), v3 = bch(q0.w);
            f16x2 v4 = bch(q1.x), v5 = bch(q1.y), v6 = bch(q1.z), v7 = bch(q1.w);
            const f16x2 oh = bch(__builtin_bit_cast(unsigned, rc.x));
            const float o0f = (float)oh.x, o1f = (float)oh.y;
            const float f2s = rc.y;
            if (has0) {
                float dt = DOT2(f1a[0], v0, 0.f);
                dt = DOT2(f1a[1], v1, dt); dt = DOT2(f1a[2], v2, dt);
                dt = DOT2(f1a[3], v3, dt); dt = DOT2(f1a[4], v4, dt);
                dt = DOT2(f1a[5], v5, dt); dt = DOT2(f1a[6], v6, dt);
                dt = DOT2(f1a[7], v7, dt);
                float e = fmaf(g2, dt, c0a);
                e = fmaf(mg, f2s, e);
                e = fmaf(gsl, a0v[j], e);
                const float w = EXP2F(e);
                s0 += w; x00 = fmaf(w, o0f, x00); x01 = fmaf(w, o1f, x01);
            }
            if (has1) {
                float dt = DOT2(f1b[0], v0, 0.f);
                dt = DOT2(f1b[1], v1, dt); dt = DOT2(f1b[2], v2, dt);
                dt = DOT2(f1b[3], v3, dt); dt = DOT2(f1b[4], v4, dt);
                dt = DOT2(f1b[5], v5, dt); dt = DOT2(f1b[6], v6, dt);
                dt = DOT2(f1b[7], v7, dt);
                float e = fmaf(g2, dt, c0b);
                e = fmaf(mg, f2s, e);
                e = fmaf(gsl, a1v[j], e);
                const float w = EXP2F(e);
                s1 += w; x10 = fmaf(w, o0f, x10); x11 = fmaf(w, o1f, x11);
            }
        }
    }

    shP[(0 * 4 + wh) * 64 + l] = s0;
    shP[(1 * 4 + wh) * 64 + l] = x00;
    shP[(2 * 4 + wh) * 64 + l] = x01;
    shP[(3 * 4 + wh) * 64 + l] = s1;
    shP[(4 * 4 + wh) * 64 + l] = x10;
    shP[(5 * 4 + wh) * 64 + l] = x11;
    __syncthreads();

    if (t < 64) {
        float v[6];
#pragma unroll
        for (int k = 0; k < 6; ++k) {
            const float* pp = &shP[k * 256 + t];
            v[k] = (pp[0] + pp[64]) + (pp[128] + pp[192]);
        }
        const int qx = t & 15, qyr = t >> 4;
        const int pp0 = (by + qyr * 2) * 128 + bx + qx;
        const float i0 = 1.0f / v[0], i1 = 1.0f / v[3];
        float* o0 = outp + (size_t)(n * 2 + 0) * HW;
        float* o1 = outp + (size_t)(n * 2 + 1) * HW;
        o0[pp0]       = v[1] * i0;
        o1[pp0]       = v[2] * i0;
        o0[pp0 + 128] = v[4] * i1;
        o1[pp0 + 128] = v[5] * i1;
    }
}

extern "C" void kernel_launch(void* const* d_in, const int* in_sizes, int n_in,
                              void* d_out, int out_size, void* d_ws, size_t ws_size,
                              hipStream_t stream) {
    const float* delta = (const float*)d_in[0];   // [4,64,128,128]
    const float* outlo = (const float*)d_in[1];   // [4,2,64,64]
    const float* ab    = (const float*)d_in[2];   // [4,81,16384]
    const float* w1    = (const float*)d_in[3];   // [16,64]
    const float* b1    = (const float*)d_in[4];   // [16]
    const float* w2    = (const float*)d_in[5];   // [16,64]
    const float* b2    = (const float*)d_in[6];   // [16]
    const float* gd    = (const float*)d_in[7];   // scalar
    const float* gs    = (const float*)d_in[8];   // scalar
    float* outp = (float*)d_out;                  // [4,2,128,128]

    uint4*  f1p4 = (uint4*)d_ws;                  // 2 MiB
    uint4*  f2p4 = f1p4 + (size_t)2 * NPIX;       // 2 MiB
    float2* recp = (float2*)(f2p4 + (size_t)2 * NPIX); // 512 KiB

    pass1_kernel<<<dim3(256, 2), dim3(256), 0, stream>>>(delta, outlo, w1, b1, w2, b2,
                                                         f1p4, f2p4, recp);
    pass2_kernel<<<dim3(8, 16, 4), dim3(256), 0, stream>>>(f1p4, f2p4, recp, ab,
                                                           gd, gs, outp);
}